// Round 12
// baseline (27.870 us; speedup 1.0000x reference)
//
#include <hip/hip_runtime.h>

#define BATCH 4096
#define FEAT  2048
#define GRID  1024           // R4 shape: 4 rows per block (one per wave)

typedef float f32x4 __attribute__((ext_vector_type(4)));
typedef unsigned long long u64;

#define CNT_SHIFT 53
#define VAL_MASK  ((1ULL << CNT_SHIFT) - 1)
#define FIX_SCALE 16777216.0f          // 2^24 fixed-point scale
// mean = total / 2^24 / BATCH = total / 2^36
#define INV_SCALE (1.0 / 68719476736.0)

// Fence-free fused reduction, R4 block shape (deconfounded from R11's 1024-thr
// blocks). Epilogue is the ONLY change vs R4/R9: the block partial travels
// THROUGH one relaxed u64 atomicAdd (low 53 bits fixed-point sum, high bits
// arrival count). Relaxed RMW emits no L2 cache-maintenance ops (R10: per-block
// acq/rel fences serialize ~58ns each). Integer adds are order-independent ->
// bit-deterministic. Last arriver holds the complete sum in the return value.
__global__ __launch_bounds__(256) void center_loss_fused(
        const float* __restrict__ x,
        const int*   __restrict__ labels,
        const float* __restrict__ centers,
        u64*         __restrict__ acc,
        float*       __restrict__ out) {
    const int wave = threadIdx.x >> 6;
    const int lane = threadIdx.x & 63;
    const int row  = (blockIdx.x << 2) | wave;

    const int lbl = labels[row];                      // wave-uniform -> scalar load
    const f32x4* __restrict__ xr = (const f32x4*)(x + (size_t)row * FEAT) + lane;
    const f32x4* __restrict__ cr = (const f32x4*)(centers + (size_t)lbl * FEAT) + lane;

    // issue all 16 loads before any arithmetic
    f32x4 xv[8], cv[8];
#pragma unroll
    for (int i = 0; i < 8; ++i)
        xv[i] = __builtin_nontemporal_load(xr + (i << 6));   // x: streamed (keeps L2 for centers)
#pragma unroll
    for (int i = 0; i < 8; ++i)
        cv[i] = cr[i << 6];                                   // centers: cacheable

    float p = 0.f;
#pragma unroll
    for (int i = 0; i < 8; ++i) {
        f32x4 d = xv[i] - cv[i];
        p += d.x * d.x + d.y * d.y + d.z * d.z + d.w * d.w;
    }

    // wave-64 butterfly reduce
#pragma unroll
    for (int off = 32; off > 0; off >>= 1)
        p += __shfl_down(p, off, 64);

    __shared__ float sw[4];
    if (lane == 0) sw[wave] = p;
    __syncthreads();

    if (threadIdx.x == 0) {
        // clamp per ROW (reference semantics), then sum the block's 4 rows
        float s = fminf(fmaxf(sw[0], 1e-12f), 1e12f)
                + fminf(fmaxf(sw[1], 1e-12f), 1e12f)
                + fminf(fmaxf(sw[2], 1e-12f), 1e12f)
                + fminf(fmaxf(sw[3], 1e-12f), 1e12f);

        const u64 q    = (u64)(s * FIX_SCALE + 0.5f);        // 53-bit fixed point
        const u64 pack = (1ULL << CNT_SHIFT) | q;
        const u64 old  = __hip_atomic_fetch_add(acc, pack,
                             __ATOMIC_RELAXED, __HIP_MEMORY_SCOPE_AGENT);
        if ((old >> CNT_SHIFT) == GRID - 1) {                // last arriver: full sum in hand
            const u64 total = (old & VAL_MASK) + q;
            out[0] = (float)((double)total * INV_SCALE);
        }
    }
}

extern "C" void kernel_launch(void* const* d_in, const int* in_sizes, int n_in,
                              void* d_out, int out_size, void* d_ws, size_t ws_size,
                              hipStream_t stream) {
    const float* x       = (const float*)d_in[0];
    const int*   labels  = (const int*)d_in[1];
    const float* centers = (const float*)d_in[2];
    float* out = (float*)d_out;
    u64*   acc = (u64*)d_ws;

    hipMemsetAsync(acc, 0, sizeof(u64), stream);
    center_loss_fused<<<GRID, 256, 0, stream>>>(x, labels, centers, acc, out);
}

// Round 13
// 19.873 us; speedup vs baseline: 1.4024x; 1.4024x over previous
//
#include <hip/hip_runtime.h>

#define BATCH  4096
#define FEAT   2048
#define GRID   1024          // R4 shape: 4 rows per block (one per wave)
#define GROUPS 32            // level-1 counters, one per group
#define BPG    (GRID / GROUPS)
#define CLINE  256           // byte spacing -> distinct cache lines / TCC channels

typedef float f32x4 __attribute__((ext_vector_type(4)));
typedef unsigned long long u64;

#define CNT_SHIFT 53
#define VAL_MASK  ((1ULL << CNT_SHIFT) - 1)
#define FIX_SCALE 16777216.0f            // 2^24 fixed point
#define INV_SCALE (1.0 / 68719476736.0)  // /2^24 /BATCH = /2^36

// Fence-free, PARALLEL-CHAIN fused reduction.
// R12 evidence: relaxed RMWs on ONE line retire at ~17ns/op (17us for 1024).
// Fix: 32 group counters on separate lines -> 32 parallel 32-op chains
// (~0.5us each, hidden under k1's staggered completions) + one 32-op
// level-2 chain. Values travel THROUGH the atomics (low 53 bits fixed-point,
// high bits arrival count): no fences, no spins, integer adds -> deterministic.
__global__ __launch_bounds__(256) void center_loss_fused(
        const float* __restrict__ x,
        const int*   __restrict__ labels,
        const float* __restrict__ centers,
        char*        __restrict__ ctrs,      // (1+GROUPS)*CLINE bytes, zeroed per call
        float*       __restrict__ out) {
    const int wave = threadIdx.x >> 6;
    const int lane = threadIdx.x & 63;
    const int row  = (blockIdx.x << 2) | wave;

    const int lbl = labels[row];                      // wave-uniform -> scalar load
    const f32x4* __restrict__ xr = (const f32x4*)(x + (size_t)row * FEAT) + lane;
    const f32x4* __restrict__ cr = (const f32x4*)(centers + (size_t)lbl * FEAT) + lane;

    // issue all 16 loads before any arithmetic
    f32x4 xv[8], cv[8];
#pragma unroll
    for (int i = 0; i < 8; ++i)
        xv[i] = __builtin_nontemporal_load(xr + (i << 6));   // x: streamed (keeps L2 for centers)
#pragma unroll
    for (int i = 0; i < 8; ++i)
        cv[i] = cr[i << 6];                                   // centers: cacheable

    float p = 0.f;
#pragma unroll
    for (int i = 0; i < 8; ++i) {
        f32x4 d = xv[i] - cv[i];
        p += d.x * d.x + d.y * d.y + d.z * d.z + d.w * d.w;
    }

    // wave-64 butterfly reduce
#pragma unroll
    for (int off = 32; off > 0; off >>= 1)
        p += __shfl_down(p, off, 64);

    __shared__ float sw[4];
    if (lane == 0) sw[wave] = p;
    __syncthreads();

    if (threadIdx.x == 0) {
        // clamp per ROW (reference semantics), then sum the block's 4 rows
        float s = fminf(fmaxf(sw[0], 1e-12f), 1e12f)
                + fminf(fmaxf(sw[1], 1e-12f), 1e12f)
                + fminf(fmaxf(sw[2], 1e-12f), 1e12f)
                + fminf(fmaxf(sw[3], 1e-12f), 1e12f);

        const u64 q = (u64)(s * FIX_SCALE + 0.5f);           // 53-bit fixed point

        // level 1: group counter (interleaved groups spread arrivals in time)
        const int g = blockIdx.x & (GROUPS - 1);
        u64* gctr = (u64*)(ctrs + (size_t)(1 + g) * CLINE);
        const u64 old1 = __hip_atomic_fetch_add(gctr, (1ULL << CNT_SHIFT) | q,
                             __ATOMIC_RELAXED, __HIP_MEMORY_SCOPE_AGENT);
        if ((old1 >> CNT_SHIFT) == BPG - 1) {                // group's last arriver
            const u64 gtot = (old1 & VAL_MASK) + q;          // full group sum in hand

            // level 2: one 32-op chain
            u64* top = (u64*)ctrs;
            const u64 old2 = __hip_atomic_fetch_add(top, (1ULL << CNT_SHIFT) | gtot,
                                 __ATOMIC_RELAXED, __HIP_MEMORY_SCOPE_AGENT);
            if ((old2 >> CNT_SHIFT) == GROUPS - 1) {         // global last arriver
                const u64 total = (old2 & VAL_MASK) + gtot;
                out[0] = (float)((double)total * INV_SCALE);
            }
        }
    }
}

extern "C" void kernel_launch(void* const* d_in, const int* in_sizes, int n_in,
                              void* d_out, int out_size, void* d_ws, size_t ws_size,
                              hipStream_t stream) {
    const float* x       = (const float*)d_in[0];
    const int*   labels  = (const int*)d_in[1];
    const float* centers = (const float*)d_in[2];
    float* out = (float*)d_out;
    char*  ctrs = (char*)d_ws;    // (1+GROUPS)*CLINE = 8448 bytes

    hipMemsetAsync(ctrs, 0, (1 + GROUPS) * CLINE, stream);
    center_loss_fused<<<GRID, 256, 0, stream>>>(x, labels, centers, ctrs, out);
}

// Round 14
// 16.081 us; speedup vs baseline: 1.7331x; 1.2357x over previous
//
#include <hip/hip_runtime.h>

#define BATCH 4096
#define FEAT  2048
#define GRID  1024   // 4 rows per block (one per wave)

typedef float f32x4 __attribute__((ext_vector_type(4)));

// R9 verbatim — best measured (15.65us). Fusion refuted 4 ways (R5/R10/R12/R13):
// any in-kernel cross-block completion costs more than the 2nd dispatch.
// k1: one WAVE per row; NT x (keeps L2 for centers); block emits ONE partial.
// k1 = 9.8us for 64MB demand = ~6.5 TB/s ~ 95% of observed fabric ceiling.
__global__ __launch_bounds__(256) void center_loss_rows(
        const float* __restrict__ x,
        const int*   __restrict__ labels,
        const float* __restrict__ centers,
        float*       __restrict__ partials) {
    const int wave = threadIdx.x >> 6;
    const int lane = threadIdx.x & 63;
    const int row  = (blockIdx.x << 2) | wave;

    const int lbl = labels[row];                      // wave-uniform -> scalar load
    const f32x4* __restrict__ xr = (const f32x4*)(x + (size_t)row * FEAT) + lane;
    const f32x4* __restrict__ cr = (const f32x4*)(centers + (size_t)lbl * FEAT) + lane;

    // issue all 16 loads before any arithmetic
    f32x4 xv[8], cv[8];
#pragma unroll
    for (int i = 0; i < 8; ++i)
        xv[i] = __builtin_nontemporal_load(xr + (i << 6));   // x: streamed
#pragma unroll
    for (int i = 0; i < 8; ++i)
        cv[i] = cr[i << 6];                                   // centers: cacheable

    float p = 0.f;
#pragma unroll
    for (int i = 0; i < 8; ++i) {
        f32x4 d = xv[i] - cv[i];
        p += d.x * d.x + d.y * d.y + d.z * d.z + d.w * d.w;
    }

    // wave-64 butterfly reduce
#pragma unroll
    for (int off = 32; off > 0; off >>= 1)
        p += __shfl_down(p, off, 64);

    __shared__ float sw[4];
    if (lane == 0) sw[wave] = p;
    __syncthreads();

    if (threadIdx.x == 0) {
        // clamp per ROW (reference semantics), then sum the block's 4 rows
        float s = fminf(fmaxf(sw[0], 1e-12f), 1e12f)
                + fminf(fmaxf(sw[1], 1e-12f), 1e12f)
                + fminf(fmaxf(sw[2], 1e-12f), 1e12f)
                + fminf(fmaxf(sw[3], 1e-12f), 1e12f);
        partials[blockIdx.x] = s;
    }
}

// kernel 2: ONE wave reduces 1024 partials (4 KB) -> mean. No LDS, no sync.
__global__ __launch_bounds__(64) void reduce_mean_kernel(
        const float* __restrict__ partials,
        float*       __restrict__ out) {
    const int lane = threadIdx.x;
    const f32x4* __restrict__ pp = (const f32x4*)partials;   // 256 x f32x4

    float s = 0.f;
#pragma unroll
    for (int i = 0; i < 4; ++i) {                   // 4 f32x4 per lane
        f32x4 v = pp[lane + (i << 6)];
        s += v.x + v.y + v.z + v.w;
    }

#pragma unroll
    for (int off = 32; off > 0; off >>= 1)
        s += __shfl_down(s, off, 64);

    if (lane == 0)
        out[0] = s * (1.0f / (float)BATCH);
}

extern "C" void kernel_launch(void* const* d_in, const int* in_sizes, int n_in,
                              void* d_out, int out_size, void* d_ws, size_t ws_size,
                              hipStream_t stream) {
    const float* x       = (const float*)d_in[0];
    const int*   labels  = (const int*)d_in[1];
    const float* centers = (const float*)d_in[2];
    float* out = (float*)d_out;
    float* partials = (float*)d_ws;   // GRID floats = 4 KB scratch

    center_loss_rows<<<GRID, 256, 0, stream>>>(x, labels, centers, partials);
    reduce_mean_kernel<<<1, 64, 0, stream>>>(partials, out);
}